// Round 1
// baseline (2439.279 us; speedup 1.0000x reference)
//
#include <hip/hip_runtime.h>
#include <hip/hip_bf16.h>
#include <hip/hip_fp16.h>

#define T_STEPS 1024
#define INC 128
#define HIDC 256
#define G3 768
#define NN 100000
#define KSPLIT 32
#define NCHUNK 3125   // NN / KSPLIT

typedef _Float16 h2 __attribute__((ext_vector_type(2)));

__device__ __forceinline__ float fdot2f(h2 a, h2 b, float c){
#if __has_builtin(__builtin_amdgcn_fdot2)
  return __builtin_amdgcn_fdot2(a, b, c, false);
#else
  return c + (float)a[0]*(float)b[0] + (float)a[1]*(float)b[1];
#endif
}

// ---------------- Phase 1: partials[ks][t][c] = sum over n-chunk of H[n,t]*X[n,c]
__global__ __launch_bounds__(256) void k_phase1(const float* __restrict__ X,
                                                const float* __restrict__ Hm,
                                                float* __restrict__ part){
  const int tt = blockIdx.x;          // 16 t-tiles of 64
  const int ks = blockIdx.y;          // 32 k-splits
  const int t0 = tt * 64;
  const int nbeg = ks * NCHUNK;
  const int nend = nbeg + NCHUNK;
  __shared__ float Hs[8][64];
  __shared__ float Xs[8][128];
  const int tid = threadIdx.x;
  const int tx = tid & 31;            // c-group: c0 = tx*4
  const int ty = tid >> 5;            // t-group: t = t0 + ty*8 .. +7
  float acc[8][4];
  #pragma unroll
  for (int r = 0; r < 8; r++){ acc[r][0]=0.f; acc[r][1]=0.f; acc[r][2]=0.f; acc[r][3]=0.f; }

  for (int n0 = nbeg; n0 < nend; n0 += 8){
    // stage 8 rows of H (64 t-cols) and X (128 c-cols)
    {
      int n = n0 + ty;
      float2 hv = {0.f, 0.f};
      float4 xv = {0.f, 0.f, 0.f, 0.f};
      if (n < nend){
        hv = *(const float2*)(Hm + (size_t)n * T_STEPS + t0 + tx * 2);
        xv = *(const float4*)(X  + (size_t)n * INC + tx * 4);
      }
      *(float2*)&Hs[ty][tx * 2] = hv;
      *(float4*)&Xs[ty][tx * 4] = xv;
    }
    __syncthreads();
    #pragma unroll
    for (int i = 0; i < 8; i++){
      float4 xr = *(const float4*)&Xs[i][tx * 4];
      float hr[8];
      *(float4*)&hr[0] = *(const float4*)&Hs[i][ty * 8];
      *(float4*)&hr[4] = *(const float4*)&Hs[i][ty * 8 + 4];
      #pragma unroll
      for (int r = 0; r < 8; r++){
        acc[r][0] += hr[r] * xr.x;
        acc[r][1] += hr[r] * xr.y;
        acc[r][2] += hr[r] * xr.z;
        acc[r][3] += hr[r] * xr.w;
      }
    }
    __syncthreads();
  }
  #pragma unroll
  for (int r = 0; r < 8; r++){
    size_t o = ((size_t)ks * T_STEPS + t0 + ty * 8 + r) * INC + tx * 4;
    float4 v = make_float4(acc[r][0], acc[r][1], acc[r][2], acc[r][3]);
    *(float4*)&part[o] = v;
  }
}

// ---------------- reduce k-splits -> visit_emb[t][c]
__global__ __launch_bounds__(256) void k_reduce(const float* __restrict__ part,
                                                float* __restrict__ ve){
  int idx = blockIdx.x * 256 + threadIdx.x;   // grid 512 -> 131072 cells
  float s = 0.f;
  #pragma unroll
  for (int ks = 0; ks < KSPLIT; ks++) s += part[(size_t)ks * (T_STEPS * INC) + idx];
  ve[idx] = s;
}

// ---------------- gx[t][j] = visit_emb[t]·w_ih[j] + b_ih[j]
__global__ __launch_bounds__(768) void k_gx(const float* __restrict__ ve,
                                            const float* __restrict__ w_ih,
                                            const float* __restrict__ b_ih,
                                            float* __restrict__ gx){
  const int t = blockIdx.x;
  const int j = threadIdx.x;
  __shared__ float4 v4[32];
  if (j < 32) v4[j] = *(const float4*)(ve + (size_t)t * INC + j * 4);
  __syncthreads();
  const float4* wr = (const float4*)(w_ih + (size_t)j * INC);
  float a0 = b_ih[j], a1 = 0.f, a2 = 0.f, a3 = 0.f;
  #pragma unroll
  for (int q = 0; q < 32; q++){
    float4 w = wr[q]; float4 v = v4[q];
    a0 += w.x * v.x; a1 += w.y * v.y; a2 += w.z * v.z; a3 += w.w * v.w;
  }
  gx[(size_t)t * G3 + j] = (a0 + a1) + (a2 + a3);
}

// ---------------- GRU scan: 1 block, 768 threads, w_hh row register-resident (fp16 pairs)
__global__ __launch_bounds__(768) void k_gru(const float* __restrict__ w_hh,
                                             const float* __restrict__ b_hh,
                                             const float* __restrict__ gx,
                                             float* __restrict__ hs){
  const int tid = threadIdx.x;            // row of w_hh / gate unit
  __shared__ float4 h16v[HIDC / 8];       // 256 halfs viewed as 32 float4
  __shared__ float h32[HIDC];
  __shared__ float rbuf[HIDC];
  __shared__ float zbuf[HIDC];
  __shared__ float nbuf[HIDC];

  h2 w[128];
  {
    const float4* wr = (const float4*)(w_hh + (size_t)tid * HIDC);
    #pragma unroll
    for (int q = 0; q < 64; q++){
      float4 v = wr[q];
      h2 p0; p0[0] = (_Float16)v.x; p0[1] = (_Float16)v.y;
      h2 p1; p1[0] = (_Float16)v.z; p1[1] = (_Float16)v.w;
      w[2 * q]     = p0;
      w[2 * q + 1] = p1;
    }
  }
  const float bias = b_hh[tid];
  if (tid < HIDC){ h32[tid] = 0.f; ((_Float16*)h16v)[tid] = (_Float16)0.f; }
  __syncthreads();

  float xg_pref = gx[tid];
  for (int t = 0; t < T_STEPS; t++){
    float xg = xg_pref;
    int tn = (t + 1 < T_STEPS) ? (t + 1) : t;
    xg_pref = gx[(size_t)tn * G3 + tid];

    float a0 = 0.f, a1 = 0.f, a2 = 0.f, a3 = 0.f;
    #pragma unroll
    for (int q = 0; q < 32; q++){
      float4 hv = h16v[q];
      h2 b0 = __builtin_bit_cast(h2, hv.x);
      h2 b1 = __builtin_bit_cast(h2, hv.y);
      h2 b2 = __builtin_bit_cast(h2, hv.z);
      h2 b3 = __builtin_bit_cast(h2, hv.w);
      a0 = fdot2f(w[4 * q + 0], b0, a0);
      a1 = fdot2f(w[4 * q + 1], b1, a1);
      a2 = fdot2f(w[4 * q + 2], b2, a2);
      a3 = fdot2f(w[4 * q + 3], b3, a3);
    }
    const float acc = (a0 + a1) + (a2 + a3) + bias;

    if (tid < HIDC){
      rbuf[tid] = 1.f / (1.f + __expf(-(xg + acc)));
    } else if (tid < 2 * HIDC){
      zbuf[tid - HIDC] = 1.f / (1.f + __expf(-(xg + acc)));
    }
    __syncthreads();
    if (tid >= 2 * HIDC){
      int i = tid - 2 * HIDC;
      float pre = xg + rbuf[i] * acc;
      float ax = fabsf(pre);
      float e = __expf(-2.f * ax);
      float th = (1.f - e) / (1.f + e);
      nbuf[i] = copysignf(th, pre);
    }
    __syncthreads();
    if (tid < HIDC){
      float z = zbuf[tid];
      float hn = (1.f - z) * nbuf[tid] + z * h32[tid];
      h32[tid] = hn;
      ((_Float16*)h16v)[tid] = (_Float16)hn;
      hs[(size_t)t * HIDC + tid] = hn;
    }
    __syncthreads();
  }
}

// ---------------- logits[t] = hs[t]·w_attn
__global__ __launch_bounds__(64) void k_logits(const float* __restrict__ hs,
                                               const float* __restrict__ w_attn,
                                               float* __restrict__ logits){
  int t = blockIdx.x;
  int l = threadIdx.x;
  float4 hv = *(const float4*)(hs + (size_t)t * HIDC + l * 4);
  float4 wv = *(const float4*)(w_attn + l * 4);
  float p = hv.x * wv.x + hv.y * wv.y + hv.z * wv.z + hv.w * wv.w;
  #pragma unroll
  for (int o = 32; o > 0; o >>= 1) p += __shfl_down(p, o);
  if (l == 0) logits[t] = p;
}

// ---------------- softmax + weighted sum -> out[256]
__global__ __launch_bounds__(1024) void k_attn(const float* __restrict__ logits,
                                               const float* __restrict__ hs,
                                               float* __restrict__ out){
  __shared__ float sm[1024];
  __shared__ float al[1024];
  __shared__ float ps[4][HIDC];
  int tid = threadIdx.x;
  float lg = logits[tid];
  sm[tid] = lg; __syncthreads();
  for (int s = 512; s > 0; s >>= 1){
    if (tid < s) sm[tid] = fmaxf(sm[tid], sm[tid + s]);
    __syncthreads();
  }
  float mx = sm[0]; __syncthreads();
  float e = __expf(lg - mx);
  sm[tid] = e; __syncthreads();
  for (int s = 512; s > 0; s >>= 1){
    if (tid < s) sm[tid] += sm[tid + s];
    __syncthreads();
  }
  float inv = 1.f / sm[0];
  al[tid] = e * inv;
  __syncthreads();
  int c = tid & 255; int tq = tid >> 8;
  float acc = 0.f;
  for (int t = tq; t < T_STEPS; t += 4) acc += al[t] * hs[(size_t)t * HIDC + c];
  ps[tq][c] = acc; __syncthreads();
  if (tid < HIDC) out[tid] = (ps[0][tid] + ps[1][tid]) + (ps[2][tid] + ps[3][tid]);
}

extern "C" void kernel_launch(void* const* d_in, const int* in_sizes, int n_in,
                              void* d_out, int out_size, void* d_ws, size_t ws_size,
                              hipStream_t stream){
  const float* X      = (const float*)d_in[0];
  const float* Hm     = (const float*)d_in[1];
  const float* w_ih   = (const float*)d_in[2];
  const float* w_hh   = (const float*)d_in[3];
  const float* b_ih   = (const float*)d_in[4];
  const float* b_hh   = (const float*)d_in[5];
  const float* w_attn = (const float*)d_in[6];
  float* out = (float*)d_out;

  float* ws     = (float*)d_ws;
  float* part   = ws;                      // 32*1024*128 = 4,194,304 f
  float* ve     = part + 4194304;          // 131,072 f
  float* gx     = ve + 131072;             // 786,432 f
  float* hs     = gx + 786432;             // 262,144 f
  float* logits = hs + 262144;             // 1,024 f   (~21.5 MB total)

  k_phase1<<<dim3(16, 32), 256, 0, stream>>>(X, Hm, part);
  k_reduce<<<512, 256, 0, stream>>>(part, ve);
  k_gx<<<1024, 768, 0, stream>>>(ve, w_ih, b_ih, gx);
  k_gru<<<1, 768, 0, stream>>>(w_hh, b_hh, gx, hs);
  k_logits<<<1024, 64, 0, stream>>>(hs, w_attn, logits);
  k_attn<<<1, 1024, 0, stream>>>(logits, hs, out);
}

// Round 3
// 2303.529 us; speedup vs baseline: 1.0589x; 1.0589x over previous
//
#include <hip/hip_runtime.h>
#include <hip/hip_fp16.h>

typedef _Float16 half8 __attribute__((ext_vector_type(8)));
typedef float f32x4 __attribute__((ext_vector_type(4)));

#define T_STEPS 1024
#define INC 128
#define HIDC 256
#define G3 768
#define NN 100000
#define KSPLIT 32
#define NCHUNK 3125   // NN / KSPLIT
#define XS_STRIDE 144 // 16 c-groups * 8 + skew(12) + hf(4): max offset 139 -> stride 144

// ---------------- Phase 1: partials[ks][t][c] = sum over n-chunk of H[n,t]*X[n,c]
// 256 blocks (8 t-tiles x 32 ksplit), 512 threads, tile 128t x 128c, thread-tile 4x8.
__global__ __launch_bounds__(512) void k_phase1(const float* __restrict__ X,
                                                const float* __restrict__ Hm,
                                                float* __restrict__ part){
  const int tt = blockIdx.x;          // 8 t-tiles of 128
  const int ks = blockIdx.y;          // 32 k-splits
  const int t0 = tt * 128;
  const int nbeg = ks * NCHUNK;
  const int nend = nbeg + NCHUNK;
  __shared__ float Hs[16][128];
  __shared__ float Xs[16 * XS_STRIDE];   // bank-skewed, stride 144 (NOT 136: see r2 bug)
  const int tid = threadIdx.x;
  const int tx = tid & 15;            // c-group: c0 = tx*8
  const int ty = tid >> 4;            // 0..31 : t rows ty*4..+3
  const int sr = tid >> 5;            // staging row 0..15
  const int sc = tid & 31;            // staging float4 col
  const int xskew = tx * 8 + (tx >> 2) * 4;   // 2-way max bank aliasing

  float acc[4][8];
  #pragma unroll
  for (int r = 0; r < 4; r++)
    #pragma unroll
    for (int q = 0; q < 8; q++) acc[r][q] = 0.f;

  for (int n0 = nbeg; n0 < nend; n0 += 16){
    int n = n0 + sr;
    float4 hv = {0.f,0.f,0.f,0.f}, xv = {0.f,0.f,0.f,0.f};
    if (n < nend){
      hv = *(const float4*)(Hm + (size_t)n * T_STEPS + t0 + sc * 4);
      xv = *(const float4*)(X  + (size_t)n * INC + sc * 4);
    }
    __syncthreads();                  // prev compute done before overwrite
    *(float4*)&Hs[sr][sc * 4] = hv;
    {
      int g = sc >> 1, hf = sc & 1;   // c-group, half
      *(float4*)&Xs[sr * XS_STRIDE + g * 8 + (g >> 2) * 4 + hf * 4] = xv;
    }
    __syncthreads();
    #pragma unroll
    for (int i = 0; i < 16; i++){
      float4 h4 = *(const float4*)&Hs[i][ty * 4];
      float4 x0 = *(const float4*)&Xs[i * XS_STRIDE + xskew];
      float4 x1 = *(const float4*)&Xs[i * XS_STRIDE + xskew + 4];
      float xr[8] = {x0.x,x0.y,x0.z,x0.w,x1.x,x1.y,x1.z,x1.w};
      float hr[4] = {h4.x,h4.y,h4.z,h4.w};
      #pragma unroll
      for (int r = 0; r < 4; r++)
        #pragma unroll
        for (int q = 0; q < 8; q++)
          acc[r][q] += hr[r] * xr[q];
    }
  }
  #pragma unroll
  for (int r = 0; r < 4; r++){
    size_t o = ((size_t)ks * T_STEPS + t0 + ty * 4 + r) * INC + tx * 8;
    *(float4*)&part[o]     = make_float4(acc[r][0], acc[r][1], acc[r][2], acc[r][3]);
    *(float4*)&part[o + 4] = make_float4(acc[r][4], acc[r][5], acc[r][6], acc[r][7]);
  }
}

// ---------------- reduce k-splits -> visit_emb[t][c]
__global__ __launch_bounds__(256) void k_reduce(const float* __restrict__ part,
                                                float* __restrict__ ve){
  int idx = blockIdx.x * 256 + threadIdx.x;   // grid 512 -> 131072 cells
  float s = 0.f;
  #pragma unroll
  for (int ks = 0; ks < KSPLIT; ks++) s += part[(size_t)ks * (T_STEPS * INC) + idx];
  ve[idx] = s;
}

// ---------------- gxq[t][unit][gate] = ve[t]·w_ih[row] + b_ih[row] (+ b_hh for r,z)
__global__ __launch_bounds__(768) void k_gx(const float* __restrict__ ve,
                                            const float* __restrict__ w_ih,
                                            const float* __restrict__ b_ih,
                                            const float* __restrict__ b_hh,
                                            float* __restrict__ gxq){
  const int t = blockIdx.x;
  const int j = threadIdx.x;          // row 0..767
  __shared__ float4 v4[32];
  if (j < 32) v4[j] = *(const float4*)(ve + (size_t)t * INC + j * 4);
  __syncthreads();
  const float4* wr = (const float4*)(w_ih + (size_t)j * INC);
  float a0 = 0.f, a1 = 0.f, a2 = 0.f, a3 = 0.f;
  #pragma unroll
  for (int q = 0; q < 32; q++){
    float4 w = wr[q]; float4 v = v4[q];
    a0 += w.x * v.x; a1 += w.y * v.y; a2 += w.z * v.z; a3 += w.w * v.w;
  }
  float bias = b_ih[j] + (j < 512 ? b_hh[j] : 0.f);
  gxq[(size_t)t * 1024 + (j & 255) * 4 + (j >> 8)] = (a0 + a1) + (a2 + a3) + bias;
}

// ---------------- GRU scan: 1 block, 1024 threads = 16 waves, MFMA GEMV.
// Wave w owns units [16w,16w+16): computes r,z,n gate rows for those units.
// A trick: all 16 A-rows = h (lane reads h[quad*8+j]) -> every D reg holds
// dot(h, w_hh[gate*256 + (lane&15) + 16w]). One barrier/step, double-buffered h.
__global__ __launch_bounds__(1024) void k_gru(const float* __restrict__ w_hh,
                                              const float* __restrict__ b_hh,
                                              const float* __restrict__ gxq,
                                              float* __restrict__ hs){
  const int tid  = threadIdx.x;
  const int w    = tid >> 6;
  const int l    = tid & 63;
  const int col  = l & 15;
  const int quad = l >> 4;
  const int unit = w * 16 + col;      // 0..255

  __shared__ _Float16 hbuf[2][256];

  // B fragments, register-resident fp16: [gate][k-chunk], 96 VGPRs
  half8 Bf[3][8];
  #pragma unroll
  for (int g = 0; g < 3; g++){
    const float* wr = w_hh + (size_t)(g * 256 + unit) * HIDC + quad * 8;
    #pragma unroll
    for (int c = 0; c < 8; c++){
      float4 v0 = *(const float4*)(wr + c * 32);
      float4 v1 = *(const float4*)(wr + c * 32 + 4);
      half8 b;
      b[0]=(_Float16)v0.x; b[1]=(_Float16)v0.y; b[2]=(_Float16)v0.z; b[3]=(_Float16)v0.w;
      b[4]=(_Float16)v1.x; b[5]=(_Float16)v1.y; b[6]=(_Float16)v1.z; b[7]=(_Float16)v1.w;
      Bf[g][c] = b;
    }
  }
  const float bn = b_hh[512 + unit];
  float hprev = 0.f;
  if (tid < 256) hbuf[0][tid] = (_Float16)0.f;
  __syncthreads();

  f32x4 gq = *(const f32x4*)(gxq + (size_t)unit * 4);   // t=0

  for (int t = 0; t < T_STEPS; t++){
    f32x4 dr = {0.f,0.f,0.f,0.f}, dz = {0.f,0.f,0.f,0.f}, dn = {0.f,0.f,0.f,0.f};
    const _Float16* hb = hbuf[t & 1];
    #pragma unroll
    for (int c = 0; c < 8; c++){
      half8 a = *(const half8*)(hb + c * 32 + quad * 8);
      dr = __builtin_amdgcn_mfma_f32_16x16x32_f16(a, Bf[0][c], dr, 0, 0, 0);
      dz = __builtin_amdgcn_mfma_f32_16x16x32_f16(a, Bf[1][c], dz, 0, 0, 0);
      dn = __builtin_amdgcn_mfma_f32_16x16x32_f16(a, Bf[2][c], dn, 0, 0, 0);
    }
    // prefetch next step's gx (pad row at t=1023)
    f32x4 gq_n = *(const f32x4*)(gxq + (size_t)(t + 1) * 1024 + unit * 4);

    float r = 1.f / (1.f + __expf(-(gq[0] + dr[0])));
    float z = 1.f / (1.f + __expf(-(gq[1] + dz[0])));
    float pre = gq[2] + r * (dn[0] + bn);
    float ax = fabsf(pre);
    float e = __expf(-2.f * ax);
    float th = (1.f - e) / (1.f + e);
    float n = copysignf(th, pre);
    float hnew = n + z * (hprev - n);
    hprev = hnew;
    if (quad == 0){
      hbuf[(t + 1) & 1][unit] = (_Float16)hnew;
      hs[(size_t)t * HIDC + unit] = hnew;
    }
    gq = gq_n;
    __syncthreads();
  }
}

// ---------------- logits[t] = hs[t]·w_attn
__global__ __launch_bounds__(64) void k_logits(const float* __restrict__ hs,
                                               const float* __restrict__ w_attn,
                                               float* __restrict__ logits){
  int t = blockIdx.x;
  int l = threadIdx.x;
  float4 hv = *(const float4*)(hs + (size_t)t * HIDC + l * 4);
  float4 wv = *(const float4*)(w_attn + l * 4);
  float p = hv.x * wv.x + hv.y * wv.y + hv.z * wv.z + hv.w * wv.w;
  #pragma unroll
  for (int o = 32; o > 0; o >>= 1) p += __shfl_down(p, o);
  if (l == 0) logits[t] = p;
}

// ---------------- softmax + weighted sum -> out[256]
__global__ __launch_bounds__(1024) void k_attn(const float* __restrict__ logits,
                                               const float* __restrict__ hs,
                                               float* __restrict__ out){
  __shared__ float sm[1024];
  __shared__ float al[1024];
  __shared__ float ps[4][HIDC];
  int tid = threadIdx.x;
  float lg = logits[tid];
  sm[tid] = lg; __syncthreads();
  for (int s = 512; s > 0; s >>= 1){
    if (tid < s) sm[tid] = fmaxf(sm[tid], sm[tid + s]);
    __syncthreads();
  }
  float mx = sm[0]; __syncthreads();
  float e = __expf(lg - mx);
  sm[tid] = e; __syncthreads();
  for (int s = 512; s > 0; s >>= 1){
    if (tid < s) sm[tid] += sm[tid + s];
    __syncthreads();
  }
  float inv = 1.f / sm[0];
  al[tid] = e * inv;
  __syncthreads();
  int c = tid & 255; int tq = tid >> 8;
  float acc = 0.f;
  for (int t = tq; t < T_STEPS; t += 4) acc += al[t] * hs[(size_t)t * HIDC + c];
  ps[tq][c] = acc; __syncthreads();
  if (tid < HIDC) out[tid] = (ps[0][tid] + ps[1][tid]) + (ps[2][tid] + ps[3][tid]);
}

extern "C" void kernel_launch(void* const* d_in, const int* in_sizes, int n_in,
                              void* d_out, int out_size, void* d_ws, size_t ws_size,
                              hipStream_t stream){
  const float* X      = (const float*)d_in[0];
  const float* Hm     = (const float*)d_in[1];
  const float* w_ih   = (const float*)d_in[2];
  const float* w_hh   = (const float*)d_in[3];
  const float* b_ih   = (const float*)d_in[4];
  const float* b_hh   = (const float*)d_in[5];
  const float* w_attn = (const float*)d_in[6];
  float* out = (float*)d_out;

  float* ws     = (float*)d_ws;
  float* part   = ws;                       // 32*1024*128 = 4,194,304 f
  float* ve     = part + 4194304;           // 131,072 f
  float* gxq    = ve + 131072;              // 1024*1024 + 1024 pad = 1,049,600 f
  float* hs     = gxq + 1049600;            // 262,144 f
  float* logits = hs + 262144;              // 1,024 f   (~22.6 MB total)

  k_phase1<<<dim3(8, 32), 512, 0, stream>>>(X, Hm, part);
  k_reduce<<<512, 256, 0, stream>>>(part, ve);
  k_gx<<<1024, 768, 0, stream>>>(ve, w_ih, b_ih, b_hh, gxq);
  k_gru<<<1, 1024, 0, stream>>>(w_hh, b_hh, gxq, hs);
  k_logits<<<1024, 64, 0, stream>>>(hs, w_attn, logits);
  k_attn<<<1, 1024, 0, stream>>>(logits, hs, out);
}